// Round 17
// baseline (82.285 us; speedup 1.0000x reference)
//
#include <hip/hip_runtime.h>
#include <hip/hip_bf16.h>
#include <math.h>

// Problem constants (fixed by the reference)
#define NPIX 256
#define HALF 128
#define NVIS 50000
#define TWO_PI_F 6.28318530717958647692f

// vis kernel geometry: 1 wave per block, 32 k's per wave (2 sets of 16)
#define VBLK 64
#define KPB  32
#define NBLK_VIS ((NVIS + KPB - 1) / KPB)   // 1563 (covers 50016; tail guarded)

typedef __attribute__((ext_vector_type(8))) short short8;
typedef __attribute__((ext_vector_type(4))) float float4v;

__device__ __forceinline__ float cell_rad_f() {
    // match reference: jnp.float32(0.005) * np.float32(pi/180/3600)
    const float arcsec = (float)(M_PI / 180.0 / 3600.0);
    return 0.005f * arcsec;
}

__device__ __forceinline__ unsigned pack_bf2(float lo, float hi) {
    // 2x f32 -> packed bf16 pair (v_cvt_pk_bf16_f32)
    __hip_bfloat162 h = __float22bfloat162_rn(make_float2(lo, hi));
    return *reinterpret_cast<unsigned*>(&h);
}

// ---------------------------------------------------------------------------
// Prep: softplus + 3x3 Hann conv (math verified R3/R6/R8), emitted as bf16 in
// 16x16x32 A-fragment order (A = image, M=16 y, K=32 x):
//   element (lane, e) = img[y = yt*16 + (lane&15)][x = step*32 + (lane>>4)*8 + e]
//   wimg[((yt*8 + step)*64 + lane)*8 + e],  yt in [0,16), step in [0,8)
// Grid: 32 blocks = (by 0..15: 16-row strip) x (xh 0..1: 128-col half).
// ---------------------------------------------------------------------------
#define SPR 18
#define SPC 130
__global__ __launch_bounds__(256) void prep_kernel(const float* __restrict__ base,
                                                   unsigned short* __restrict__ wimg) {
    __shared__ float sp[SPR][SPC];
    const int by = blockIdx.x >> 1, xh = blockIdx.x & 1;
    const int y0 = by * 16, x0 = xh * 128;
    const int tid = threadIdx.x;

    for (int idx = tid; idx < SPR * SPC; idx += 256) {
        int r = idx / SPC, c = idx - r * SPC;
        int y = y0 - 1 + r, x = x0 - 1 + c;
        float v = 0.f;
        if ((unsigned)y < NPIX && (unsigned)x < NPIX)
            v = log1pf(expf(base[y * NPIX + x]));
        sp[r][c] = v;
    }
    __syncthreads();

    // one conv octet per thread: yl = tid>>4 (row), oc = tid&15 (8-px column run)
    {
        int yl = tid >> 4, oc = tid & 15;
        union { unsigned short u[8]; uint4 v; } pk;
        #pragma unroll
        for (int e = 0; e < 8; ++e) {
            int cl = oc * 8 + e;     // sp col of conv-center-minus-1
            float top = sp[yl    ][cl] + 2.f * sp[yl    ][cl + 1] + sp[yl    ][cl + 2];
            float mid = sp[yl + 1][cl] + 2.f * sp[yl + 1][cl + 1] + sp[yl + 1][cl + 2];
            float bot = sp[yl + 2][cl] + 2.f * sp[yl + 2][cl + 1] + sp[yl + 2][cl + 2];
            float cv  = 0.0625f * (top + 2.f * mid + bot);
            __hip_bfloat16 h = __float2bfloat16(cv);
            pk.u[e] = *reinterpret_cast<unsigned short*>(&h);
        }
        // global octet: y = by*16 + yl, x0g = xh*128 + oc*8
        int step = xh * 4 + (oc >> 2);       // (x0g)>>5
        int hi   = oc & 3;                   // ((x0g)>>3)&3
        size_t off = (((size_t)by * 8 + step) * 64 + hi * 16 + yl) * 8;
        *(uint4*)(wimg + off) = pk.v;
    }
}

// Build one B phase-fragment table: x = step*32 + hi*8 + e, value exp(-i*DEL*(x-128))
#define BUILD_B(DEL, BRE, BIM)                                             \
    {                                                                      \
        float cd_, sd_; sincosf((DEL), &sd_, &cd_);                        \
        const float x1r_ = cd_, x1i_ = -sd_;                               \
        float xr_ = x1r_, xi_ = x1i_;                                      \
        _Pragma("unroll")                                                  \
        for (int q = 0; q < 5; ++q) {                                      \
            float nr_ = fmaf(xr_, xr_, -xi_ * xi_);                        \
            float ni_ = 2.f * xr_ * xi_;                                   \
            xr_ = nr_; xi_ = ni_;                                          \
        }                                                                  \
        const float x32r_ = xr_, x32i_ = xi_;                              \
        float th0_ = (DEL) * (float)(hi * 8 - HALF);                       \
        float s0_, c0_; sincosf(th0_, &s0_, &c0_);                         \
        float bar_ = c0_, bai_ = -s0_;                                     \
        _Pragma("unroll")                                                  \
        for (int step = 0; step < 8; ++step) {                             \
            float ar_ = bar_, ai_ = bai_;                                  \
            _Pragma("unroll")                                              \
            for (int ep = 0; ep < 4; ++ep) {                               \
                float ar1_ = fmaf(ar_, x1r_, -ai_ * x1i_);                 \
                float ai1_ = fmaf(ai_, x1r_,  ar_ * x1i_);                 \
                BRE[step].u[ep] = pack_bf2(ar_, ar1_);                     \
                BIM[step].u[ep] = pack_bf2(ai_, ai1_);                     \
                ar_ = fmaf(ar1_, x1r_, -ai1_ * x1i_);                      \
                ai_ = fmaf(ai1_, x1r_,  ar1_ * x1i_);                      \
            }                                                              \
            float nbr_ = fmaf(bar_, x32r_, -bai_ * x32i_);                 \
            float nbi_ = fmaf(bai_, x32r_,  bar_ * x32i_);                 \
            bar_ = nbr_; bai_ = nbi_;                                      \
        }                                                                  \
    }

// Build y-phase state: b[r] = exp(-i*EPS*(hi*4+r-128)), step rot = exp(-i*16*EPS)
#define BUILD_Y(EPS, Y16R, Y16I, BR, BI)                                   \
    {                                                                      \
        float ce_, se_; sincosf((EPS), &se_, &ce_);                        \
        const float y1r_ = ce_, y1i_ = -se_;                               \
        float yr_ = y1r_, yi_ = y1i_;                                      \
        _Pragma("unroll")                                                  \
        for (int q = 0; q < 4; ++q) {                                      \
            float nr_ = fmaf(yr_, yr_, -yi_ * yi_);                        \
            float ni_ = 2.f * yr_ * yi_;                                   \
            yr_ = nr_; yi_ = ni_;                                          \
        }                                                                  \
        Y16R = yr_; Y16I = yi_;                                            \
        float w0_ = (EPS) * (float)(hi * 4 - HALF);                        \
        float sw_, cw_; sincosf(w0_, &sw_, &cw_);                          \
        BR[0] = cw_; BI[0] = -sw_;                                         \
        _Pragma("unroll")                                                  \
        for (int r = 1; r < 4; ++r) {                                      \
            BR[r] = fmaf(BR[r-1], y1r_, -BI[r-1] * y1i_);                  \
            BI[r] = fmaf(BI[r-1], y1r_,  BR[r-1] * y1i_);                  \
        }                                                                  \
    }

// ---------------------------------------------------------------------------
// Vis: 16x16x32 bf16 MFMA NUDFT, TWO k-sets per wave (KPB=32): each loaded
// A-fragment feeds 4 MFMAs (Re/Im x 2 sets) -> L2 traffic halves vs R16
// (200 MB total; was the binding constraint). Mappings HW-verified (R8):
//   A row = lane&15 (y), K-elem = (lane>>4)*8+e (x)
//   B col = lane&15 (k), K-elem = (lane>>4)*8+e (x)
//   C/D  col = lane&15 (k), row = (lane>>4)*4+reg (y)
// Register budget (R12/R13 lesson): B 2x64=128 + A batch 16 + acc 16 +
// y-state 20 + misc ~45 = ~225 <= 256 (launch_bounds(64,2)). A single-
// buffered in 4-frag batches; 1563 waves fit one occupancy round.
// Output planar f32 [re-plane][im-plane] (verified R6).
// ---------------------------------------------------------------------------
__global__ __launch_bounds__(VBLK, 2) void vis_mfma(const float* __restrict__ uu,
                                                    const float* __restrict__ vv,
                                                    const unsigned short* __restrict__ wimg,
                                                    float* __restrict__ out) {
    const int lane = threadIdx.x & 63;
    const int lo = lane & 15, hi = lane >> 4;
    const int k0  = blockIdx.x * KPB;
    const int k0a = k0 + lo;                     // set-0 k (unclamped)
    const int k0b = k0 + 16 + lo;                // set-1 k (unclamped)
    const int kaA = (k0a < NVIS) ? k0a : (NVIS - 1);
    const int kaB = (k0b < NVIS) ? k0b : (NVIS - 1);

    const float cell = cell_rad_f();
    const float sc   = TWO_PI_F * 1e3f * cell;
    const float delA = sc * uu[kaA], epsA = sc * vv[kaA];
    const float delB = sc * uu[kaB], epsB = sc * vv[kaB];

    union BF { short8 v; unsigned u[4]; };
    BF Bre0[8], Bim0[8], Bre1[8], Bim1[8];
    BUILD_B(delA, Bre0, Bim0)
    BUILD_B(delB, Bre1, Bim1)

    float y16rA, y16iA, brA[4], biA[4];
    float y16rB, y16iB, brB[4], biB[4];
    BUILD_Y(epsA, y16rA, y16iA, brA, biA)
    BUILD_Y(epsB, y16rB, y16iB, brB, biB)

    float visrA = 0.f, visiA = 0.f, visrB = 0.f, visiB = 0.f;
    const short8* __restrict__ Afrag = (const short8*)wimg;  // idx = (yt*8+step)*64+lane

    #pragma unroll
    for (int yt = 0; yt < 16; ++yt) {
        float4v aR0 = {0.f, 0.f, 0.f, 0.f}, aI0 = {0.f, 0.f, 0.f, 0.f};
        float4v aR1 = {0.f, 0.f, 0.f, 0.f}, aI1 = {0.f, 0.f, 0.f, 0.f};

        #pragma unroll
        for (int b = 0; b < 2; ++b) {
            short8 A[4];
            #pragma unroll
            for (int j = 0; j < 4; ++j)
                A[j] = Afrag[((yt * 8 + b * 4 + j) * 64) + lane];
            #pragma unroll
            for (int j = 0; j < 4; ++j) {
                aR0 = __builtin_amdgcn_mfma_f32_16x16x32_bf16(A[j], Bre0[b * 4 + j].v, aR0, 0, 0, 0);
                aI0 = __builtin_amdgcn_mfma_f32_16x16x32_bf16(A[j], Bim0[b * 4 + j].v, aI0, 0, 0, 0);
                aR1 = __builtin_amdgcn_mfma_f32_16x16x32_bf16(A[j], Bre1[b * 4 + j].v, aR1, 0, 0, 0);
                aI1 = __builtin_amdgcn_mfma_f32_16x16x32_bf16(A[j], Bim1[b * 4 + j].v, aI1, 0, 0, 0);
            }
        }

        // epilogue set 0: vis += T*b per r; then b[r] *= rot16y
        #pragma unroll
        for (int r = 0; r < 4; ++r) {
            visrA = fmaf(aR0[r], brA[r], visrA); visrA = fmaf(-aI0[r], biA[r], visrA);
            visiA = fmaf(aI0[r], brA[r], visiA); visiA = fmaf( aR0[r], biA[r], visiA);
            float nr = fmaf(brA[r], y16rA, -biA[r] * y16iA);
            float ni = fmaf(biA[r], y16rA,  brA[r] * y16iA);
            brA[r] = nr; biA[r] = ni;
        }
        // epilogue set 1
        #pragma unroll
        for (int r = 0; r < 4; ++r) {
            visrB = fmaf(aR1[r], brB[r], visrB); visrB = fmaf(-aI1[r], biB[r], visrB);
            visiB = fmaf(aI1[r], brB[r], visiB); visiB = fmaf( aR1[r], biB[r], visiB);
            float nr = fmaf(brB[r], y16rB, -biB[r] * y16iB);
            float ni = fmaf(biB[r], y16rB,  brB[r] * y16iB);
            brB[r] = nr; biB[r] = ni;
        }
    }

    // reduce over hi-groups (lanes lane^16, lane^32 span the 4 y-row groups)
    visrA += __shfl_xor(visrA, 16); visrA += __shfl_xor(visrA, 32);
    visiA += __shfl_xor(visiA, 16); visiA += __shfl_xor(visiA, 32);
    visrB += __shfl_xor(visrB, 16); visrB += __shfl_xor(visrB, 32);
    visiB += __shfl_xor(visiB, 16); visiB += __shfl_xor(visiB, 32);

    if (hi == 0) {
        const float c2 = cell * cell;
        if (k0a < NVIS) {
            out[k0a]        = visrA * c2;   // real plane
            out[NVIS + k0a] = visiA * c2;   // imag plane
        }
        if (k0b < NVIS) {
            out[k0b]        = visrB * c2;
            out[NVIS + k0b] = visiB * c2;
        }
    }
}

extern "C" void kernel_launch(void* const* d_in, const int* in_sizes, int n_in,
                              void* d_out, int out_size, void* d_ws, size_t ws_size,
                              hipStream_t stream) {
    const float* base = (const float*)d_in[0];   // (1,256,256) f32
    const float* uu   = (const float*)d_in[1];   // (50000,) f32
    const float* vv   = (const float*)d_in[2];   // (50000,) f32
    (void)in_sizes; (void)n_in; (void)out_size; (void)ws_size;

    unsigned short* wimg = (unsigned short*)d_ws;    // 128 KB fragment-ordered bf16 image

    prep_kernel<<<32, 256, 0, stream>>>(base, wimg);
    vis_mfma<<<NBLK_VIS, VBLK, 0, stream>>>(uu, vv, wimg, (float*)d_out);
}

// Round 18
// 79.796 us; speedup vs baseline: 1.0312x; 1.0312x over previous
//
#include <hip/hip_runtime.h>
#include <hip/hip_bf16.h>
#include <math.h>

// Problem constants (fixed by the reference)
#define NPIX 256
#define HALF 128
#define NVIS 50000
#define TWO_PI_F 6.28318530717958647692f

// vis kernel geometry: 1 wave per block, 32 k's per wave (2 sets of 16)
#define VBLK 64
#define KPB  32
#define NBLK_VIS ((NVIS + KPB - 1) / KPB)   // 1563 (covers 50016; tail guarded)

typedef __attribute__((ext_vector_type(8))) short short8;
typedef __attribute__((ext_vector_type(4))) float float4v;

__device__ __forceinline__ float cell_rad_f() {
    // match reference: jnp.float32(0.005) * np.float32(pi/180/3600)
    const float arcsec = (float)(M_PI / 180.0 / 3600.0);
    return 0.005f * arcsec;
}

__device__ __forceinline__ unsigned pack_bf2(float lo, float hi) {
    // 2x f32 -> packed bf16 pair (v_cvt_pk_bf16_f32)
    __hip_bfloat162 h = __float22bfloat162_rn(make_float2(lo, hi));
    return *reinterpret_cast<unsigned*>(&h);
}

// ---------------------------------------------------------------------------
// Prep: softplus + 3x3 Hann conv (math verified R3/R6/R8), emitted as bf16 in
// 16x16x32 A-fragment order (A = image, M=16 y, K=32 x):
//   element (lane, e) = img[y = yt*16 + (lane&15)][x = step*32 + (lane>>4)*8 + e]
//   wimg[((yt*8 + step)*64 + lane)*8 + e],  yt in [0,16), step in [0,8)
// Grid: 32 blocks = (by 0..15: 16-row strip) x (xh 0..1: 128-col half).
// ---------------------------------------------------------------------------
#define SPR 18
#define SPC 130
__global__ __launch_bounds__(256) void prep_kernel(const float* __restrict__ base,
                                                   unsigned short* __restrict__ wimg) {
    __shared__ float sp[SPR][SPC];
    const int by = blockIdx.x >> 1, xh = blockIdx.x & 1;
    const int y0 = by * 16, x0 = xh * 128;
    const int tid = threadIdx.x;

    for (int idx = tid; idx < SPR * SPC; idx += 256) {
        int r = idx / SPC, c = idx - r * SPC;
        int y = y0 - 1 + r, x = x0 - 1 + c;
        float v = 0.f;
        if ((unsigned)y < NPIX && (unsigned)x < NPIX)
            v = log1pf(expf(base[y * NPIX + x]));
        sp[r][c] = v;
    }
    __syncthreads();

    // one conv octet per thread: yl = tid>>4 (row), oc = tid&15 (8-px column run)
    {
        int yl = tid >> 4, oc = tid & 15;
        union { unsigned short u[8]; uint4 v; } pk;
        #pragma unroll
        for (int e = 0; e < 8; ++e) {
            int cl = oc * 8 + e;     // sp col of conv-center-minus-1
            float top = sp[yl    ][cl] + 2.f * sp[yl    ][cl + 1] + sp[yl    ][cl + 2];
            float mid = sp[yl + 1][cl] + 2.f * sp[yl + 1][cl + 1] + sp[yl + 1][cl + 2];
            float bot = sp[yl + 2][cl] + 2.f * sp[yl + 2][cl + 1] + sp[yl + 2][cl + 2];
            float cv  = 0.0625f * (top + 2.f * mid + bot);
            __hip_bfloat16 h = __float2bfloat16(cv);
            pk.u[e] = *reinterpret_cast<unsigned short*>(&h);
        }
        // global octet: y = by*16 + yl, x0g = xh*128 + oc*8
        int step = xh * 4 + (oc >> 2);       // (x0g)>>5
        int hi   = oc & 3;                   // ((x0g)>>3)&3
        size_t off = (((size_t)by * 8 + step) * 64 + hi * 16 + yl) * 8;
        *(uint4*)(wimg + off) = pk.v;
    }
}

// Build one B phase-fragment table: x = step*32 + hi*8 + e, value exp(-i*DEL*(x-128))
#define BUILD_B(DEL, BRE, BIM)                                             \
    {                                                                      \
        float cd_, sd_; sincosf((DEL), &sd_, &cd_);                        \
        const float x1r_ = cd_, x1i_ = -sd_;                               \
        float xr_ = x1r_, xi_ = x1i_;                                      \
        _Pragma("unroll")                                                  \
        for (int q = 0; q < 5; ++q) {                                      \
            float nr_ = fmaf(xr_, xr_, -xi_ * xi_);                        \
            float ni_ = 2.f * xr_ * xi_;                                   \
            xr_ = nr_; xi_ = ni_;                                          \
        }                                                                  \
        const float x32r_ = xr_, x32i_ = xi_;                              \
        float th0_ = (DEL) * (float)(hi * 8 - HALF);                       \
        float s0_, c0_; sincosf(th0_, &s0_, &c0_);                         \
        float bar_ = c0_, bai_ = -s0_;                                     \
        _Pragma("unroll")                                                  \
        for (int step = 0; step < 8; ++step) {                             \
            float ar_ = bar_, ai_ = bai_;                                  \
            _Pragma("unroll")                                              \
            for (int ep = 0; ep < 4; ++ep) {                               \
                float ar1_ = fmaf(ar_, x1r_, -ai_ * x1i_);                 \
                float ai1_ = fmaf(ai_, x1r_,  ar_ * x1i_);                 \
                BRE[step].u[ep] = pack_bf2(ar_, ar1_);                     \
                BIM[step].u[ep] = pack_bf2(ai_, ai1_);                     \
                ar_ = fmaf(ar1_, x1r_, -ai1_ * x1i_);                      \
                ai_ = fmaf(ai1_, x1r_,  ar1_ * x1i_);                      \
            }                                                              \
            float nbr_ = fmaf(bar_, x32r_, -bai_ * x32i_);                 \
            float nbi_ = fmaf(bai_, x32r_,  bar_ * x32i_);                 \
            bar_ = nbr_; bai_ = nbi_;                                      \
        }                                                                  \
    }

// Build y-phase state: b[r] = exp(-i*EPS*(hi*4+r-128)), step rot = exp(-i*16*EPS)
#define BUILD_Y(EPS, Y16R, Y16I, BR, BI)                                   \
    {                                                                      \
        float ce_, se_; sincosf((EPS), &se_, &ce_);                        \
        const float y1r_ = ce_, y1i_ = -se_;                               \
        float yr_ = y1r_, yi_ = y1i_;                                      \
        _Pragma("unroll")                                                  \
        for (int q = 0; q < 4; ++q) {                                      \
            float nr_ = fmaf(yr_, yr_, -yi_ * yi_);                        \
            float ni_ = 2.f * yr_ * yi_;                                   \
            yr_ = nr_; yi_ = ni_;                                          \
        }                                                                  \
        Y16R = yr_; Y16I = yi_;                                            \
        float w0_ = (EPS) * (float)(hi * 4 - HALF);                        \
        float sw_, cw_; sincosf(w0_, &sw_, &cw_);                          \
        BR[0] = cw_; BI[0] = -sw_;                                         \
        _Pragma("unroll")                                                  \
        for (int r = 1; r < 4; ++r) {                                      \
            BR[r] = fmaf(BR[r-1], y1r_, -BI[r-1] * y1i_);                  \
            BI[r] = fmaf(BI[r-1], y1r_,  BR[r-1] * y1i_);                  \
        }                                                                  \
    }

// ---------------------------------------------------------------------------
// Vis: 16x16x32 bf16 MFMA NUDFT. R18 = R17 (two k-sets/wave, halved L2
// traffic) + R16 (2-deep software-pipelined A prefetch). Each A-fragment
// batch's loads issue BEFORE the previous batch's 16 MFMAs; fully unrolled,
// static indices (rule #20). Mappings HW-verified (R8):
//   A row = lane&15 (y), K-elem = (lane>>4)*8+e (x)
//   B col = lane&15 (k), K-elem = (lane>>4)*8+e (x)
//   C/D  col = lane&15 (k), row = (lane>>4)*4+reg (y)
// Register budget (R12/R13 lesson): B 2x64=128 + A 2x16=32 + acc 16 +
// y-state 20 + misc ~45 = ~240 <= 256 (launch_bounds(64,2)).
// Output planar f32 [re-plane][im-plane] (verified R6).
// ---------------------------------------------------------------------------
__global__ __launch_bounds__(VBLK, 2) void vis_mfma(const float* __restrict__ uu,
                                                    const float* __restrict__ vv,
                                                    const unsigned short* __restrict__ wimg,
                                                    float* __restrict__ out) {
    const int lane = threadIdx.x & 63;
    const int lo = lane & 15, hi = lane >> 4;
    const int k0  = blockIdx.x * KPB;
    const int k0a = k0 + lo;                     // set-0 k (unclamped)
    const int k0b = k0 + 16 + lo;                // set-1 k (unclamped)
    const int kaA = (k0a < NVIS) ? k0a : (NVIS - 1);
    const int kaB = (k0b < NVIS) ? k0b : (NVIS - 1);

    const float cell = cell_rad_f();
    const float sc   = TWO_PI_F * 1e3f * cell;
    const float delA = sc * uu[kaA], epsA = sc * vv[kaA];
    const float delB = sc * uu[kaB], epsB = sc * vv[kaB];

    union BF { short8 v; unsigned u[4]; };
    BF Bre0[8], Bim0[8], Bre1[8], Bim1[8];
    BUILD_B(delA, Bre0, Bim0)
    BUILD_B(delB, Bre1, Bim1)

    float y16rA, y16iA, brA[4], biA[4];
    float y16rB, y16iB, brB[4], biB[4];
    BUILD_Y(epsA, y16rA, y16iA, brA, biA)
    BUILD_Y(epsB, y16rB, y16iB, brB, biB)

    float visrA = 0.f, visiA = 0.f, visrB = 0.f, visiB = 0.f;
    const short8* __restrict__ Afrag = (const short8*)wimg;  // idx = (yt*8+step)*64+lane

    // --- pipelined loop over 32 batches (16 yt x 2 halves), 2-deep dbuf ---
    short8 Abuf[2][4];
    #pragma unroll
    for (int j = 0; j < 4; ++j) Abuf[0][j] = Afrag[(j * 64) + lane];

    #pragma unroll
    for (int yt = 0; yt < 16; ++yt) {
        float4v aR0 = {0.f, 0.f, 0.f, 0.f}, aI0 = {0.f, 0.f, 0.f, 0.f};
        float4v aR1 = {0.f, 0.f, 0.f, 0.f}, aI1 = {0.f, 0.f, 0.f, 0.f};

        #pragma unroll
        for (int b = 0; b < 2; ++b) {
            const int bat = yt * 2 + b;          // global batch index
            const int cur = bat & 1, nxt = cur ^ 1;  // static after unroll

            if (bat < 31) {
                #pragma unroll
                for (int j = 0; j < 4; ++j)
                    Abuf[nxt][j] = Afrag[(((bat + 1) * 4 + j) * 64) + lane];
            }

            #pragma unroll
            for (int j = 0; j < 4; ++j) {
                aR0 = __builtin_amdgcn_mfma_f32_16x16x32_bf16(Abuf[cur][j], Bre0[b * 4 + j].v, aR0, 0, 0, 0);
                aI0 = __builtin_amdgcn_mfma_f32_16x16x32_bf16(Abuf[cur][j], Bim0[b * 4 + j].v, aI0, 0, 0, 0);
                aR1 = __builtin_amdgcn_mfma_f32_16x16x32_bf16(Abuf[cur][j], Bre1[b * 4 + j].v, aR1, 0, 0, 0);
                aI1 = __builtin_amdgcn_mfma_f32_16x16x32_bf16(Abuf[cur][j], Bim1[b * 4 + j].v, aI1, 0, 0, 0);
            }
        }

        // epilogue set 0: vis += T*b per r; then b[r] *= rot16y
        #pragma unroll
        for (int r = 0; r < 4; ++r) {
            visrA = fmaf(aR0[r], brA[r], visrA); visrA = fmaf(-aI0[r], biA[r], visrA);
            visiA = fmaf(aI0[r], brA[r], visiA); visiA = fmaf( aR0[r], biA[r], visiA);
            float nr = fmaf(brA[r], y16rA, -biA[r] * y16iA);
            float ni = fmaf(biA[r], y16rA,  brA[r] * y16iA);
            brA[r] = nr; biA[r] = ni;
        }
        // epilogue set 1
        #pragma unroll
        for (int r = 0; r < 4; ++r) {
            visrB = fmaf(aR1[r], brB[r], visrB); visrB = fmaf(-aI1[r], biB[r], visrB);
            visiB = fmaf(aI1[r], brB[r], visiB); visiB = fmaf( aR1[r], biB[r], visiB);
            float nr = fmaf(brB[r], y16rB, -biB[r] * y16iB);
            float ni = fmaf(biB[r], y16rB,  brB[r] * y16iB);
            brB[r] = nr; biB[r] = ni;
        }
    }

    // reduce over hi-groups (lanes lane^16, lane^32 span the 4 y-row groups)
    visrA += __shfl_xor(visrA, 16); visrA += __shfl_xor(visrA, 32);
    visiA += __shfl_xor(visiA, 16); visiA += __shfl_xor(visiA, 32);
    visrB += __shfl_xor(visrB, 16); visrB += __shfl_xor(visrB, 32);
    visiB += __shfl_xor(visiB, 16); visiB += __shfl_xor(visiB, 32);

    if (hi == 0) {
        const float c2 = cell * cell;
        if (k0a < NVIS) {
            out[k0a]        = visrA * c2;   // real plane
            out[NVIS + k0a] = visiA * c2;   // imag plane
        }
        if (k0b < NVIS) {
            out[k0b]        = visrB * c2;
            out[NVIS + k0b] = visiB * c2;
        }
    }
}

extern "C" void kernel_launch(void* const* d_in, const int* in_sizes, int n_in,
                              void* d_out, int out_size, void* d_ws, size_t ws_size,
                              hipStream_t stream) {
    const float* base = (const float*)d_in[0];   // (1,256,256) f32
    const float* uu   = (const float*)d_in[1];   // (50000,) f32
    const float* vv   = (const float*)d_in[2];   // (50000,) f32
    (void)in_sizes; (void)n_in; (void)out_size; (void)ws_size;

    unsigned short* wimg = (unsigned short*)d_ws;    // 128 KB fragment-ordered bf16 image

    prep_kernel<<<32, 256, 0, stream>>>(base, wimg);
    vis_mfma<<<NBLK_VIS, VBLK, 0, stream>>>(uu, vv, wimg, (float*)d_out);
}